// Round 9
// baseline (349.966 us; speedup 1.0000x reference)
//
#include <hip/hip_runtime.h>

// Problem constants (match reference)
#define TT 20      // timesteps
#define GG 1024    // groups
#define PP 64      // pedestrians per group
#define THR 0.25f

typedef float f32x4 __attribute__((ext_vector_type(4)));

// LDS-only barrier (no vmcnt drain). Only 2 per block, around staging.
#define BARRIER_LDS() asm volatile("s_waitcnt lgkmcnt(0)\n\ts_barrier" ::: "memory")

// R9: write-stream locality experiment.
//   grid = 1024 blocks x 512 threads; block = ONE full group -> writes one
//   contiguous 320 KB region, sweeping forward (chunk c -> rows c*8..c*8+7,
//   40 KB each). Bijective XCD swizzle (1024 = 8*128 exact): XCD x gets
//   g in [128x,128x+128) in launch order, so each XCD's store stream is one
//   dense forward sweep over a contiguous 40 MB slab (mimics the rocclr
//   fill's moving-window pattern instead of 1500 scattered write pointers).
// Everything else as R8: lane l holds ped l's trajectory in regs, xi via
// readlane (SGPR broadcast), swizzled wave-private in-LDS transpose
// (pi(m)=(m&~7)|((5m)&7), conflict-free b128 both sides), lane-contiguous
// 1 KB nontemporal wave stores, no barriers in the main loop.
__global__ __launch_bounds__(512) void traj_critic_kernel(
    const float* __restrict__ traj, float* __restrict__ out)
{
    __shared__ float4 buf[8 * 320];   // 40 KB; first 640 double as staging

    const int bid  = blockIdx.x;
    const int g    = ((bid & 7) << 7) | (bid >> 3);   // XCD-contiguous groups
    const int tid  = threadIdx.x;
    const int lane = tid & 63;
    const int wid  = tid >> 6;        // 0..7

    // ---- stage group's (T,P,2) f32 -> LDS, layout [t][p] float2 ----
    {
        const float4* tg = (const float4*)traj;
        for (int u = tid; u < 640; u += 512) {
            int t = u >> 5;            // 32 float4 per timestep row
            int r = u & 31;
            buf[u] = tg[t * 32768 + g * 32 + r];
        }
    }
    BARRIER_LDS();

    // per-lane trajectory of ped j = lane (40 VGPRs)
    float2 xj[TT];
    const float2* xs2 = (const float2*)buf;
#pragma unroll
    for (int t = 0; t < TT; ++t) xj[t] = xs2[t * 64 + lane];
    BARRIER_LDS();   // staging reads done before wid 0/1 overwrite the area

    const int wbase = wid * 320;                    // wave-private float4 slice
    f32x4* outg4 = (f32x4*)out + (size_t)g * 20480;

#pragma unroll 1
    for (int c = 0; c < 8; ++c) {
        const int i = c * 8 + wid;                  // this wave's row
        const float kill = (i == lane) ? 0.0f : 1.0f;

        float cst[TT];
#pragma unroll
        for (int t = 0; t < TT; ++t) {
            float xix = __int_as_float(
                __builtin_amdgcn_readlane(__float_as_int(xj[t].x), i));
            float xiy = __int_as_float(
                __builtin_amdgcn_readlane(__float_as_int(xj[t].y), i));
            float dx = xix - xj[t].x;
            float dy = xiy - xj[t].y;
            float d  = __builtin_amdgcn_sqrtf(dx * dx + dy * dy);
            float v  = THR - d;
            v = v > 0.0f ? v : 0.0f;
            cst[t] = v * kill;                      // diagonal -> 0
        }

        // swizzled wave-private transpose: 5x ds_write_b128, conflict-free
#pragma unroll
        for (int kt = 0; kt < 5; ++kt) {
            int m  = wbase + 5 * lane + kt;
            int pm = (m & ~7) | ((5 * m) & 7);
            buf[pm] = make_float4(cst[4 * kt + 0], cst[4 * kt + 1],
                                  cst[4 * kt + 2], cst[4 * kt + 3]);
        }

        // same-wave read-back + nontemporal lane-contiguous stores
        f32x4* op = outg4 + (size_t)i * 320;
#pragma unroll
        for (int k = 0; k < 5; ++k) {
            int m  = wbase + k * 64 + lane;
            int pm = (m & ~7) | ((5 * m) & 7);
            float4 v = buf[pm];
            f32x4 nv = { v.x, v.y, v.z, v.w };
            __builtin_nontemporal_store(nv, &op[k * 64 + lane]);
        }
    }
}

extern "C" void kernel_launch(void* const* d_in, const int* in_sizes, int n_in,
                              void* d_out, int out_size, void* d_ws, size_t ws_size,
                              hipStream_t stream) {
    const float* traj = (const float*)d_in[0];  // (T, B, 2) f32
    float* out = (float*)d_out;                 // G*P*P*T f32
    traj_critic_kernel<<<GG, 512, 0, stream>>>(traj, out);
}